// Round 5
// baseline (454.435 us; speedup 1.0000x reference)
//
#include <hip/hip_runtime.h>
#include <math.h>

#define VOL (96*96*96)
#define KCLS 5
#define CZ 8              // z-outputs per block
#define PSTR 64           // swizzled plane x-stride (shorts); 16B-chunk XOR swizzle
#define PROWS 40          // staged plane y-rows (32 + 8 halo)
#define PSZ (PROWS*PSTR)  // 2560 shorts per plane buffer
#define NS2 15            // distinct s2 = dy^2+dz^2 values

typedef __attribute__((ext_vector_type(8))) short bf16x8;
typedef __attribute__((ext_vector_type(4))) float f32x4;
typedef __attribute__((ext_vector_type(4))) unsigned short us4;

constexpr int S2VALS[NS2] = {0,1,2,4,5,8,9,10,13,16,17,18,20,25,32};
constexpr int MAP33[33] = {0,1,2,-1,3,4,-1,-1,5,6,7,-1,-1,8,-1,-1,
                           9,10,11,-1,12,-1,-1,-1,-1,13,-1,-1,-1,-1,-1,-1,14};

__device__ __forceinline__ unsigned short f2bf(float f) {
  unsigned u = __builtin_bit_cast(unsigned, f);
  u += 0x7fffu + ((u >> 16) & 1u);
  return (unsigned short)(u >> 16);
}

// ws layout (doubles):
//  [32..351]  sumL partials:  32 + (b*5+k)*32 + slot32
//  [352..671] sumIL partials: 352 + (b*5+k)*32 + slot32
//  [672..751] numer partials: 672 + kcl*16 + slot16
//  [752..831] denom partials: 752 + kcl*16 + slot16

// ---------------- kernel A: per-(b,k) sums of L and I*L (I read once) ----------------
__global__ __launch_bounds__(256) void k_sums(const float* __restrict__ I,
                                              const float* __restrict__ L,
                                              double* __restrict__ ws) {
  const int b = blockIdx.y;
  const int base = blockIdx.x * 256 + threadIdx.x;    // float4 index; 864*256 = VOL/4
  const float4 iv = ((const float4*)(I + b * VOL))[base];
  float sL[KCLS], sIL[KCLS];
#pragma unroll
  for (int k = 0; k < KCLS; ++k) {
    const float4 lv = ((const float4*)(L + (b * KCLS + k) * VOL))[base];
    sL[k] = (lv.x + lv.y) + (lv.z + lv.w);
    sIL[k] = iv.x * lv.x + iv.y * lv.y + iv.z * lv.z + iv.w * lv.w;
  }
#pragma unroll
  for (int k = 0; k < KCLS; ++k) {
#pragma unroll
    for (int off = 32; off; off >>= 1) {
      sL[k] += __shfl_down(sL[k], off);
      sIL[k] += __shfl_down(sIL[k], off);
    }
  }
  __shared__ double red[4][2 * KCLS];
  const int wid = threadIdx.x >> 6;
  if ((threadIdx.x & 63) == 0) {
#pragma unroll
    for (int k = 0; k < KCLS; ++k) {
      red[wid][k] = (double)sL[k];
      red[wid][KCLS + k] = (double)sIL[k];
    }
  }
  __syncthreads();
  if (threadIdx.x < 2 * KCLS) {
    double v = red[0][threadIdx.x] + red[1][threadIdx.x] + red[2][threadIdx.x] + red[3][threadIdx.x];
    const int k = threadIdx.x % KCLS;
    const int which = threadIdx.x / KCLS;
    const int slot = blockIdx.x & 31;
    atomicAdd(&ws[32 + which * 320 + (b * KCLS + k) * 32 + slot], v);
  }
}

// ---------------- kernel B: MFMA banded-matmul 3D conv ----------------
__global__ __launch_bounds__(256, 4) void k_conv(const float* __restrict__ I,
                                                 const float* __restrict__ L,
                                                 double* __restrict__ ws) {
  __shared__ __attribute__((aligned(16))) short Wp[2][PSZ];
  __shared__ __attribute__((aligned(16))) short LWp[2][PSZ];
  __shared__ double red[8];
  __shared__ float meanS;

  const int t = threadIdx.x;
  const int vol = blockIdx.z;
  const int kcl = vol % KCLS;
  const int b = vol / KCLS;
  const int x0 = (blockIdx.x % 3) * 32;
  const int y0 = (blockIdx.x / 3) * 32;
  const int z0 = blockIdx.y * CZ;

  const float* __restrict__ Ib = I + b * VOL;
  const float* __restrict__ Lb = L + vol * VOL;

  // ---- inline reduce of this volume's partial sums -> mean ----
  if (t < 64) {
    double a = (t < 32) ? ws[32 + vol * 32 + t] : 0.0;
    double c = (t < 32) ? ws[352 + vol * 32 + t] : 0.0;
#pragma unroll
    for (int off = 16; off; off >>= 1) {
      a += __shfl_down(a, off);
      c += __shfl_down(c, off);
    }
    if (t == 0) meanS = (float)(c / (a + 1e-5 * (double)VOL));
  }
  __syncthreads();
  const float mean = meanS;

  // ---- lane constants ----
  const int lane = t & 63;
  const int w = t >> 6;
  const int wx = w & 1, wy = w >> 1;
  const int nn = lane & 15, qq = lane >> 4;
  const int gyOut = y0 + 16 * wy + nn;
  const int gxOut = x0 + 16 * wx + 4 * qq;

  // ---- A-fragments computed per-lane in registers (no LDS table) ----
  bf16x8 afr[NS2];
#pragma unroll
  for (int r = 0; r < NS2; ++r) {
    const float s2c = (float)S2VALS[r];
    bf16x8 v;
#pragma unroll
    for (int j = 0; j < 8; ++j) {
      const int dx = 8 * qq + j - nn;     // k - m
      float val = 0.f;
      if (dx >= 0 && dx <= 8) {
        const float q = s2c + (float)((dx - 4) * (dx - 4));
        val = __expf(-0.02f * q * q);
      }
      v[j] = (short)f2bf(val);
    }
    afr[r] = v;
  }

  f32x4 accW[9], accL[9];
  const f32x4 zer = {0.f, 0.f, 0.f, 0.f};
#pragma unroll
  for (int i = 0; i < 9; ++i) { accW[i] = zer; accL[i] = zer; }
  float pN = 0.f, pD = 0.f;

  // ---- staging helpers ----
  auto loadQuad = [&](int zp, int qi, float4& iv, float4& lv, bool& ok) {
    const int row = qi / 12;
    const int xq = (qi - row * 12) * 4;
    const int gy = y0 - 4 + row, gx = x0 - 4 + xq;
    ok = ((unsigned)zp < 96u) && ((unsigned)gy < 96u) && ((unsigned)gx <= 92u);
    if (ok) {
      const int off = (zp * 96 + gy) * 96 + gx;
      iv = *(const float4*)(Ib + off);
      lv = *(const float4*)(Lb + off);
    } else {
      iv = make_float4(0.f, 0.f, 0.f, 0.f);
      lv = make_float4(0.f, 0.f, 0.f, 0.f);
    }
  };
  auto storeQuad = [&](int buf, int qi, const float4& iv, const float4& lv, bool ok) {
    const int row = qi / 12;
    const int q = qi - row * 12;
    const int c = q >> 1, o = (q & 1) << 2;
    const int a = row * PSTR + (((c ^ (row & 7)) << 3) + o);
    float d, w0, w1, w2, w3;
    d = iv.x - mean; d = d * d; w0 = ok ? __expf(-d * d) : 0.f;
    d = iv.y - mean; d = d * d; w1 = ok ? __expf(-d * d) : 0.f;
    d = iv.z - mean; d = d * d; w2 = ok ? __expf(-d * d) : 0.f;
    d = iv.w - mean; d = d * d; w3 = ok ? __expf(-d * d) : 0.f;
    us4 wv = { f2bf(w0), f2bf(w1), f2bf(w2), f2bf(w3) };
    us4 ov = { f2bf(lv.x * w0), f2bf(lv.y * w1), f2bf(lv.z * w2), f2bf(lv.w * w3) };
    *(us4*)(&Wp[buf][a]) = wv;
    *(us4*)(&LWp[buf][a]) = ov;
  };

  auto computeEdge = [&](int buf, int iLo, int iHi) {
    const short* __restrict__ Wb = Wp[buf];
    const short* __restrict__ Lwb = LWp[buf];
#pragma unroll
    for (int dy = 0; dy < 9; ++dy) {
      const int dy2c = (dy - 4) * (dy - 4);
      const int yrow = 16 * wy + nn + dy;
      const int boff = yrow * PSTR + ((((2 * wx + qq) ^ (yrow & 7))) << 3);
      const bf16x8 bw = *(const bf16x8*)(Wb + boff);
      const bf16x8 bl = *(const bf16x8*)(Lwb + boff);
#pragma unroll
      for (int i = 0; i < 9; ++i) {
        if (i >= iLo && i <= iHi) {
          const int da = (i < 4) ? (4 - i) : (i - 4);
          const int ri = MAP33[dy2c + da * da];
          accW[i] = __builtin_amdgcn_mfma_f32_16x16x32_bf16(afr[ri], bw, accW[i], 0, 0, 0);
          accL[i] = __builtin_amdgcn_mfma_f32_16x16x32_bf16(afr[ri], bl, accL[i], 0, 0, 0);
        }
      }
    }
  };

  // ---- stage plane 0 ----
  {
    float4 i0, l0, i1, l1; bool o0, o1;
    loadQuad(z0 - 4, t, i0, l0, o0);
    storeQuad(0, t, i0, l0, o0);
    if (t < 224) { loadQuad(z0 - 4, 256 + t, i1, l1, o1); storeQuad(0, 256 + t, i1, l1, o1); }
  }
  __syncthreads();

  // ---- main z-pipeline ----
  const int zp0 = z0 - 4;
  const int zend = z0 + CZ + 4;   // exclusive
  for (int zp = zp0; zp < zend; ++zp) {
    const int cur = (zp - zp0) & 1;
    const bool more = (zp + 1 < zend);
    float4 i0, l0, i1, l1; bool o0 = false, o1 = false;
    if (more) {
      loadQuad(zp + 1, t, i0, l0, o0);
      if (t < 224) loadQuad(zp + 1, 256 + t, i1, l1, o1);
    }
    // prefetch label row for this iteration's retire
    const int zo = zp - 4;
    const bool lok = (zo >= z0) && (zo < z0 + CZ);
    float4 lab = make_float4(0.f, 0.f, 0.f, 0.f);
    if (lok) lab = *(const float4*)(Lb + (zo * 96 + gyOut) * 96 + gxOut);

    if ((unsigned)zp <= 95u) {
      int iLo = z0 - zo; if (iLo < 0) iLo = 0;
      int iHi = (z0 + CZ - 1) - zo; if (iHi > 8) iHi = 8;
      computeEdge(cur, iLo, iHi);
    }
    // retire acc slot 0 then slide the ring
    if (lok) {
      pN += accL[0].x * lab.x + accL[0].y * lab.y + accL[0].z * lab.z + accL[0].w * lab.w;
      pD += accW[0].x * lab.x + accW[0].y * lab.y + accW[0].z * lab.z + accW[0].w * lab.w;
    }
#pragma unroll
    for (int i = 0; i < 8; ++i) { accW[i] = accW[i + 1]; accL[i] = accL[i + 1]; }
    accW[8] = zer; accL[8] = zer;

    if (more) {
      storeQuad(cur ^ 1, t, i0, l0, o0);
      if (t < 224) storeQuad(cur ^ 1, 256 + t, i1, l1, o1);
    }
    __syncthreads();
  }

  // ---- reduce & accumulate (spread atomics over 16 slots) ----
#pragma unroll
  for (int off = 32; off; off >>= 1) {
    pN += __shfl_down(pN, off);
    pD += __shfl_down(pD, off);
  }
  if (lane == 0) { red[w] = (double)pN; red[4 + w] = (double)pD; }
  __syncthreads();
  if (t == 0) {
    const int slot = (blockIdx.x + blockIdx.y) & 15;
    atomicAdd(&ws[672 + kcl * 16 + slot], red[0] + red[1] + red[2] + red[3]);
    atomicAdd(&ws[752 + kcl * 16 + slot], red[4] + red[5] + red[6] + red[7]);
  }
}

// ---------------- kernel C: finalize ----------------
__global__ void k_final(const double* __restrict__ ws, float* __restrict__ out) {
  __shared__ double acc[KCLS];
  const int t = threadIdx.x;
  if (t < KCLS) {
    double n = 0.0, d = 0.0;
#pragma unroll
    for (int s = 0; s < 16; ++s) {
      n += ws[672 + t * 16 + s];
      d += ws[752 + t * 16 + s];
    }
    acc[t] = fabs(n / (d + 1e-6));
  }
  __syncthreads();
  if (t == 0) {
    double loss = acc[0] + acc[1] + acc[2] + acc[3] + acc[4];
    out[0] = (float)(5.0 - loss);
  }
}

extern "C" void kernel_launch(void* const* d_in, const int* in_sizes, int n_in,
                              void* d_out, int out_size, void* d_ws, size_t ws_size,
                              hipStream_t stream) {
  (void)in_sizes; (void)n_in; (void)out_size; (void)ws_size;
  const float* I = (const float*)d_in[0];
  const float* L = (const float*)d_in[1];
  double* ws = (double*)d_ws;
  float* out = (float*)d_out;

  hipMemsetAsync(d_ws, 0, 832 * sizeof(double), stream);
  k_sums<<<dim3(864, 2, 1), 256, 0, stream>>>(I, L, ws);
  k_conv<<<dim3(9, 12, 10), 256, 0, stream>>>(I, L, ws);
  k_final<<<1, 64, 0, stream>>>(ws, out);
}

// Round 6
// 184.434 us; speedup vs baseline: 2.4639x; 2.4639x over previous
//
#include <hip/hip_runtime.h>
#include <math.h>

#define VOL (96*96*96)
#define KCLS 5
#define CZ 12             // z-outputs per block; grid 720 = all-resident at 3 blocks/CU
#define PSTR 64           // swizzled plane x-stride (shorts); 16B-chunk XOR swizzle
#define PROWS 40          // staged plane y-rows (32 + 8 halo)
#define PSZ (PROWS*PSTR)  // 2560 shorts per plane buffer
#define NS2 15            // distinct s2 = dy^2+dz^2 values

typedef __attribute__((ext_vector_type(8))) short bf16x8;
typedef __attribute__((ext_vector_type(4))) float f32x4;
typedef __attribute__((ext_vector_type(4))) unsigned short us4;

constexpr int S2VALS[NS2] = {0,1,2,4,5,8,9,10,13,16,17,18,20,25,32};
constexpr int MAP33[33] = {0,1,2,-1,3,4,-1,-1,5,6,7,-1,-1,8,-1,-1,
                           9,10,11,-1,12,-1,-1,-1,-1,13,-1,-1,-1,-1,-1,-1,14};

__device__ __forceinline__ unsigned short f2bf(float f) {
  unsigned u = __builtin_bit_cast(unsigned, f);
  u += 0x7fffu + ((u >> 16) & 1u);
  return (unsigned short)(u >> 16);
}

// ws layout (doubles):
//  [32..351]  sumL partials:  32 + (b*5+k)*32 + slot32
//  [352..671] sumIL partials: 352 + (b*5+k)*32 + slot32
//  [672..751] numer partials: 672 + kcl*16 + slot16
//  [752..831] denom partials: 752 + kcl*16 + slot16

// ---------------- kernel A: per-(b,k) sums of L and I*L ----------------
__global__ __launch_bounds__(256) void k_sums(const float* __restrict__ I,
                                              const float* __restrict__ L,
                                              double* __restrict__ ws) {
  const int b = blockIdx.y;
  const int base = blockIdx.x * 256 + threadIdx.x;    // float4 index; 864*256 = VOL/4
  const float4 iv = ((const float4*)(I + b * VOL))[base];
  float sL[KCLS], sIL[KCLS];
#pragma unroll
  for (int k = 0; k < KCLS; ++k) {
    const float4 lv = ((const float4*)(L + (b * KCLS + k) * VOL))[base];
    sL[k] = (lv.x + lv.y) + (lv.z + lv.w);
    sIL[k] = iv.x * lv.x + iv.y * lv.y + iv.z * lv.z + iv.w * lv.w;
  }
#pragma unroll
  for (int k = 0; k < KCLS; ++k) {
#pragma unroll
    for (int off = 32; off; off >>= 1) {
      sL[k] += __shfl_down(sL[k], off);
      sIL[k] += __shfl_down(sIL[k], off);
    }
  }
  __shared__ double red[4][2 * KCLS];
  const int wid = threadIdx.x >> 6;
  if ((threadIdx.x & 63) == 0) {
#pragma unroll
    for (int k = 0; k < KCLS; ++k) {
      red[wid][k] = (double)sL[k];
      red[wid][KCLS + k] = (double)sIL[k];
    }
  }
  __syncthreads();
  if (threadIdx.x < 2 * KCLS) {
    double v = red[0][threadIdx.x] + red[1][threadIdx.x] + red[2][threadIdx.x] + red[3][threadIdx.x];
    const int k = threadIdx.x % KCLS;
    const int which = threadIdx.x / KCLS;
    const int slot = blockIdx.x & 31;
    atomicAdd(&ws[32 + which * 320 + (b * KCLS + k) * 32 + slot], v);
  }
}

// ---------------- kernel B: MFMA banded-matmul 3D conv ----------------
// afr[15] in regs; B-fragment dy-pipeline hides LDS latency; reg cap 3 waves/SIMD.
__global__ __launch_bounds__(256, 3) void k_conv(const float* __restrict__ I,
                                                 const float* __restrict__ L,
                                                 double* __restrict__ ws) {
  __shared__ __attribute__((aligned(16))) short Wp[2][PSZ];
  __shared__ __attribute__((aligned(16))) short LWp[2][PSZ];
  __shared__ double red[8];
  __shared__ float meanS;

  const int t = threadIdx.x;
  const int vol = blockIdx.z;
  const int kcl = vol % KCLS;
  const int b = vol / KCLS;
  const int x0 = (blockIdx.x % 3) * 32;
  const int y0 = (blockIdx.x / 3) * 32;
  const int z0 = blockIdx.y * CZ;

  const float* __restrict__ Ib = I + b * VOL;
  const float* __restrict__ Lb = L + vol * VOL;

  // ---- inline reduce of this volume's partial sums -> mean ----
  if (t < 32) {
    double a = ws[32 + vol * 32 + t];
    double c = ws[352 + vol * 32 + t];
#pragma unroll
    for (int off = 16; off; off >>= 1) {
      a += __shfl_down(a, off);
      c += __shfl_down(c, off);
    }
    if (t == 0) meanS = (float)(c / (a + 1e-5 * (double)VOL));
  }
  __syncthreads();
  const float mean = meanS;

  // ---- lane constants ----
  const int lane = t & 63;
  const int w = t >> 6;
  const int wx = w & 1, wy = w >> 1;
  const int nn = lane & 15, qq = lane >> 4;
  const int gyOut = y0 + 16 * wy + nn;
  const int gxOut = x0 + 16 * wx + 4 * qq;

  // ---- A-fragments computed per-lane in registers ----
  bf16x8 afr[NS2];
#pragma unroll
  for (int r = 0; r < NS2; ++r) {
    const float s2c = (float)S2VALS[r];
    bf16x8 v;
#pragma unroll
    for (int j = 0; j < 8; ++j) {
      const int dx = 8 * qq + j - nn;     // k - m
      float val = 0.f;
      if (dx >= 0 && dx <= 8) {
        const float q = s2c + (float)((dx - 4) * (dx - 4));
        val = __expf(-0.02f * q * q);
      }
      v[j] = (short)f2bf(val);
    }
    afr[r] = v;
  }

  f32x4 accW[9], accL[9];
  const f32x4 zer = {0.f, 0.f, 0.f, 0.f};
#pragma unroll
  for (int i = 0; i < 9; ++i) { accW[i] = zer; accL[i] = zer; }
  float pN = 0.f, pD = 0.f;

  // ---- stage one z-plane (zp in [0,95]) into buffer buf ----
  auto stagePlane = [&](int buf, int zp) {
#pragma unroll
    for (int ii = 0; ii < 2; ++ii) {
      const int qi = t + ii * 256;
      if (qi < 480) {
        const int row = qi / 12;
        const int q = qi - row * 12;
        const int xq = q * 4;
        const int gy = y0 - 4 + row, gx = x0 - 4 + xq;
        const bool ok = ((unsigned)gy < 96u) && ((unsigned)gx <= 92u);
        float4 iv = make_float4(0.f, 0.f, 0.f, 0.f);
        float4 lv = make_float4(0.f, 0.f, 0.f, 0.f);
        if (ok) {
          const int off = (zp * 96 + gy) * 96 + gx;
          iv = *(const float4*)(Ib + off);
          lv = *(const float4*)(Lb + off);
        }
        float d, w0, w1, w2, w3;
        d = iv.x - mean; d = d * d; w0 = ok ? __expf(-d * d) : 0.f;
        d = iv.y - mean; d = d * d; w1 = ok ? __expf(-d * d) : 0.f;
        d = iv.z - mean; d = d * d; w2 = ok ? __expf(-d * d) : 0.f;
        d = iv.w - mean; d = d * d; w3 = ok ? __expf(-d * d) : 0.f;
        us4 wv = { f2bf(w0), f2bf(w1), f2bf(w2), f2bf(w3) };
        us4 ov = { f2bf(lv.x * w0), f2bf(lv.y * w1), f2bf(lv.z * w2), f2bf(lv.w * w3) };
        const int c = q >> 1, o = (q & 1) << 2;
        const int a = row * PSTR + (((c ^ (row & 7)) << 3) + o);
        *(us4*)(&Wp[buf][a]) = wv;
        *(us4*)(&LWp[buf][a]) = ov;
      }
    }
  };

  // ---- pipelined plane compute: prefetch B(dy+1) before MFMA burst on dy ----
  auto computeEdge = [&](int buf, int iLo, int iHi) {
    const short* __restrict__ Wb = Wp[buf];
    const short* __restrict__ Lwb = LWp[buf];
    const int yb = 16 * wy + nn;
    const int csel = 2 * wx + qq;
    int boff = yb * PSTR + (((csel ^ (yb & 7))) << 3);
    bf16x8 bw = *(const bf16x8*)(Wb + boff);
    bf16x8 bl = *(const bf16x8*)(Lwb + boff);
#pragma unroll
    for (int dy = 0; dy < 9; ++dy) {
      bf16x8 nbw, nbl;
      if (dy < 8) {
        const int yrow = yb + dy + 1;
        const int nboff = yrow * PSTR + (((csel ^ (yrow & 7))) << 3);
        nbw = *(const bf16x8*)(Wb + nboff);
        nbl = *(const bf16x8*)(Lwb + nboff);
      }
      const int dy2c = (dy - 4) * (dy - 4);
#pragma unroll
      for (int i = 0; i < 9; ++i) {
        if (i >= iLo && i <= iHi) {
          const int da = (i < 4) ? (4 - i) : (i - 4);
          const int ri = MAP33[dy2c + da * da];
          accW[i] = __builtin_amdgcn_mfma_f32_16x16x32_bf16(afr[ri], bw, accW[i], 0, 0, 0);
          accL[i] = __builtin_amdgcn_mfma_f32_16x16x32_bf16(afr[ri], bl, accL[i], 0, 0, 0);
        }
      }
      bw = nbw; bl = nbl;
    }
  };

  // ---- main z-pipeline: one barrier per plane ----
  const int zp0 = z0 - 4;
  const int zend = z0 + CZ + 4;   // exclusive
  if ((unsigned)zp0 <= 95u) stagePlane(0, zp0);
  __syncthreads();

  for (int zp = zp0; zp < zend; ++zp) {
    const int cur = (zp - zp0) & 1;
    const int zo = zp - 4;
    const bool lok = (zo >= z0) && (zo < z0 + CZ);
    float4 lab = make_float4(0.f, 0.f, 0.f, 0.f);
    if (lok) lab = *(const float4*)(Lb + (zo * 96 + gyOut) * 96 + gxOut);

    if ((unsigned)zp <= 95u) {
      int iLo = z0 - zo; if (iLo < 0) iLo = 0;
      int iHi = (z0 + CZ - 1) - zo; if (iHi > 8) iHi = 8;
      computeEdge(cur, iLo, iHi);
    }
    if (lok) {
      pN += accL[0].x * lab.x + accL[0].y * lab.y + accL[0].z * lab.z + accL[0].w * lab.w;
      pD += accW[0].x * lab.x + accW[0].y * lab.y + accW[0].z * lab.z + accW[0].w * lab.w;
    }
#pragma unroll
    for (int i = 0; i < 8; ++i) { accW[i] = accW[i + 1]; accL[i] = accL[i + 1]; }
    accW[8] = zer; accL[8] = zer;

    const int zn = zp + 1;
    if (zn < zend && (unsigned)zn <= 95u) stagePlane(cur ^ 1, zn);
    __syncthreads();
  }

  // ---- reduce & accumulate (spread atomics over 16 slots) ----
#pragma unroll
  for (int off = 32; off; off >>= 1) {
    pN += __shfl_down(pN, off);
    pD += __shfl_down(pD, off);
  }
  if (lane == 0) { red[w] = (double)pN; red[4 + w] = (double)pD; }
  __syncthreads();
  if (t == 0) {
    const int slot = (blockIdx.x + blockIdx.y) & 15;
    atomicAdd(&ws[672 + kcl * 16 + slot], red[0] + red[1] + red[2] + red[3]);
    atomicAdd(&ws[752 + kcl * 16 + slot], red[4] + red[5] + red[6] + red[7]);
  }
}

// ---------------- kernel C: finalize ----------------
__global__ void k_final(const double* __restrict__ ws, float* __restrict__ out) {
  __shared__ double acc[KCLS];
  const int t = threadIdx.x;
  if (t < KCLS) {
    double n = 0.0, d = 0.0;
#pragma unroll
    for (int s = 0; s < 16; ++s) {
      n += ws[672 + t * 16 + s];
      d += ws[752 + t * 16 + s];
    }
    acc[t] = fabs(n / (d + 1e-6));
  }
  __syncthreads();
  if (t == 0) {
    double loss = acc[0] + acc[1] + acc[2] + acc[3] + acc[4];
    out[0] = (float)(5.0 - loss);
  }
}

extern "C" void kernel_launch(void* const* d_in, const int* in_sizes, int n_in,
                              void* d_out, int out_size, void* d_ws, size_t ws_size,
                              hipStream_t stream) {
  (void)in_sizes; (void)n_in; (void)out_size; (void)ws_size;
  const float* I = (const float*)d_in[0];
  const float* L = (const float*)d_in[1];
  double* ws = (double*)d_ws;
  float* out = (float*)d_out;

  hipMemsetAsync(d_ws, 0, 832 * sizeof(double), stream);
  k_sums<<<dim3(864, 2, 1), 256, 0, stream>>>(I, L, ws);
  k_conv<<<dim3(9, 8, 10), 256, 0, stream>>>(I, L, ws);
  k_final<<<1, 64, 0, stream>>>(ws, out);
}